// Round 10
// baseline (598.084 us; speedup 1.0000x reference)
//
#include <hip/hip_runtime.h>
#include <hip/hip_bf16.h>
#include <cstdint>
#include <cstddef>

// Problem constants (B,C,H,W)=(2,128,192,192), K=4, O=60
constexpr int kB = 2, kC = 128, kH = 192, kW = 192, kK = 4, kO = 60;
constexpr int kHW  = kH * kW;        // 36864
constexpr int NPIX = kB * kHW;       // 73728
constexpr int PT   = 128;            // pixels per block
constexpr int NB   = NPIX / PT;      // 576 blocks
constexpr int MAXR = 192;            // 128 rows + 4*15 pad slack, rounded
constexpr float kSlope = 0.01f;

typedef __attribute__((ext_vector_type(8))) short bf16x8;
typedef __attribute__((ext_vector_type(4))) float f32x4;

// ---------------- dtype helpers ----------------
__device__ __forceinline__ unsigned short f2bf(float f) {
  unsigned u = __float_as_uint(f);
  u += 0x7FFF + ((u >> 16) & 1);
  return (unsigned short)(u >> 16);
}
__device__ __forceinline__ float bf2f(unsigned short u) {
  return __uint_as_float(((unsigned)u) << 16);
}
__device__ __forceinline__ bf16x8 load_wfrag(const __hip_bfloat16* p) {
  return *reinterpret_cast<const bf16x8*>(p);
}
__device__ __forceinline__ bf16x8 load_wfrag(const float* p) {
  bf16x8 r;
#pragma unroll
  for (int j = 0; j < 8; ++j) r[j] = (short)f2bf(p[j]);
  return r;
}
__device__ __forceinline__ f32x4 load_bias4(const float* p) {
  const float4 v = *reinterpret_cast<const float4*>(p);
  f32x4 r; r[0] = v.x; r[1] = v.y; r[2] = v.z; r[3] = v.w; return r;
}
__device__ __forceinline__ f32x4 load_bias4(const __hip_bfloat16* p) {
  const short4 v = *reinterpret_cast<const short4*>(p);
  f32x4 r;
  r[0] = bf2f((unsigned short)v.x); r[1] = bf2f((unsigned short)v.y);
  r[2] = bf2f((unsigned short)v.z); r[3] = bf2f((unsigned short)v.w);
  return r;
}

// LDS row swizzle: row = 128 bf16 = 16 groups of 8; group g of row r at xgrp(r,g)*8.
__device__ __forceinline__ int xgrp(int r, int g) {
  return (g + r + (r >> 3)) & 15;
}

// ---------------- MFMA layer on a pair of 16-px column tiles -----------------
// A[m=lane&15][k=quad*8+j] (weight rows, 64B-line L2 reads, shared by pair);
// B[n=pix][k] from swizzled LDS; D: col=pix, row=quad*4+reg  [m89-verified].
// No __syncthreads: pair rows are wave-private; lgkmcnt orders ds ops.
template<typename T, bool LRELU, bool RES, bool SAVEH>
__device__ __forceinline__ void layer_pair(unsigned short (*X)[kC],
                                           int pa, int pb,
                                           const T* __restrict__ Wk,
                                           const T* __restrict__ bk,
                                           short4 (&h0)[8], short4 (&h1)[8],
                                           int quad, int col) {
  bf16x8 B0[4], B1[4];
#pragma unroll
  for (int ks = 0; ks < 4; ++ks) {
    B0[ks] = *reinterpret_cast<const bf16x8*>(&X[pa][xgrp(pa, ks * 4 + quad) * 8]);
    B1[ks] = *reinterpret_cast<const bf16x8*>(&X[pb][xgrp(pb, ks * 4 + quad) * 8]);
  }
  f32x4 acc0[8], acc1[8];
#pragma unroll
  for (int r = 0; r < 8; ++r) {
    const f32x4 bias = load_bias4(bk + r * 16 + quad * 4);
    f32x4 a0 = bias, a1 = bias;
#pragma unroll
    for (int ks = 0; ks < 4; ++ks) {
      const bf16x8 A = load_wfrag(Wk + (size_t)(r * 16 + col) * kC + ks * 32 + quad * 8);
      a0 = __builtin_amdgcn_mfma_f32_16x16x32_bf16(A, B0[ks], a0, 0, 0, 0);
      a1 = __builtin_amdgcn_mfma_f32_16x16x32_bf16(A, B1[ks], a1, 0, 0, 0);
    }
    acc0[r] = a0; acc1[r] = a1;
  }
#pragma unroll
  for (int r = 0; r < 8; ++r) {
    const int nb = r * 16 + quad * 4;
    float v0[4], v1[4];
#pragma unroll
    for (int j = 0; j < 4; ++j) {
      float t0 = acc0[r][j], t1 = acc1[r][j];
      if constexpr (LRELU) { t0 = fmaxf(t0, kSlope * t0); t1 = fmaxf(t1, kSlope * t1); }
      v0[j] = t0; v1[j] = t1;
    }
    if constexpr (RES) {
      v0[0] += bf2f((unsigned short)h0[r].x); v0[1] += bf2f((unsigned short)h0[r].y);
      v0[2] += bf2f((unsigned short)h0[r].z); v0[3] += bf2f((unsigned short)h0[r].w);
      v1[0] += bf2f((unsigned short)h1[r].x); v1[1] += bf2f((unsigned short)h1[r].y);
      v1[2] += bf2f((unsigned short)h1[r].z); v1[3] += bf2f((unsigned short)h1[r].w);
    }
    short4 p0, p1;
    p0.x = (short)f2bf(v0[0]); p0.y = (short)f2bf(v0[1]);
    p0.z = (short)f2bf(v0[2]); p0.w = (short)f2bf(v0[3]);
    p1.x = (short)f2bf(v1[0]); p1.y = (short)f2bf(v1[1]);
    p1.z = (short)f2bf(v1[2]); p1.w = (short)f2bf(v1[3]);
    if constexpr (SAVEH) { h0[r] = p0; h1[r] = p1; }
    *reinterpret_cast<short4*>(&X[pa][xgrp(pa, nb >> 3) * 8 + (nb & 7)]) = p0;
    *reinterpret_cast<short4*>(&X[pb][xgrp(pb, nb >> 3) * 8 + (nb & 7)]) = p1;
  }
}

// final layer: 60 outs -> 64-short prefix of each pixel row (rotated groups)
template<typename T>
__device__ __forceinline__ void layer5(unsigned short (*X)[kC],
                                       int pa, int pb,
                                       const T* __restrict__ Wk,
                                       const T* __restrict__ bk,
                                       int quad, int col) {
  bf16x8 B0[4], B1[4];
#pragma unroll
  for (int ks = 0; ks < 4; ++ks) {
    B0[ks] = *reinterpret_cast<const bf16x8*>(&X[pa][xgrp(pa, ks * 4 + quad) * 8]);
    B1[ks] = *reinterpret_cast<const bf16x8*>(&X[pb][xgrp(pb, ks * 4 + quad) * 8]);
  }
#pragma unroll
  for (int r = 0; r < 4; ++r) {
    const f32x4 bias = load_bias4(bk + min(r * 16 + quad * 4, 56));
    f32x4 a0 = bias, a1 = bias;
    const size_t row = (size_t)min(r * 16 + col, kO - 1) * kC;
#pragma unroll
    for (int ks = 0; ks < 4; ++ks) {
      const bf16x8 A = load_wfrag(Wk + row + ks * 32 + quad * 8);
      a0 = __builtin_amdgcn_mfma_f32_16x16x32_bf16(A, B0[ks], a0, 0, 0, 0);
      a1 = __builtin_amdgcn_mfma_f32_16x16x32_bf16(A, B1[ks], a1, 0, 0, 0);
    }
    const int gi = r * 4 + quad;            // channel group gi -> ch gi*4..+3
    short4 p0, p1;
    p0.x = (short)f2bf(a0[0]); p0.y = (short)f2bf(a0[1]);
    p0.z = (short)f2bf(a0[2]); p0.w = (short)f2bf(a0[3]);
    p1.x = (short)f2bf(a1[0]); p1.y = (short)f2bf(a1[1]);
    p1.z = (short)f2bf(a1[2]); p1.w = (short)f2bf(a1[3]);
    *reinterpret_cast<short4*>(&X[pa][((gi + pa) & 15) * 4]) = p0;
    *reinterpret_cast<short4*>(&X[pb][((gi + pb) & 15) * 4]) = p1;
  }
}

// ---------------- staging: coalesced x -> class-sorted swizzled LDS ----------
__device__ __forceinline__ void stage(const __hip_bfloat16* x, size_t base,
                                      unsigned short (*X)[kC],
                                      const int* sortIdx, int tid) {
  const unsigned short* xs = (const unsigned short*)x;
#pragma unroll
  for (int s = 0; s < 2; ++s) {
#pragma unroll
    for (int cc = 0; cc < 4; ++cc) {
      const int c  = cc * 32 + (tid >> 3);
      const int p0 = (tid & 7) * 8;
      bf16x8 v = *reinterpret_cast<const bf16x8*>(xs + base + (size_t)c * kHW + s * 64 + p0);
#pragma unroll
      for (int j = 0; j < 8; ++j) {
        const int row = sortIdx[s * 64 + p0 + j];
        X[row][xgrp(row, c >> 3) * 8 + (c & 7)] = (unsigned short)v[j];
      }
    }
  }
}
__device__ __forceinline__ void stage(const float* x, size_t base,
                                      unsigned short (*X)[kC],
                                      const int* sortIdx, int tid) {
#pragma unroll
  for (int s = 0; s < 2; ++s) {
#pragma unroll
    for (int i = 0; i < 8; ++i) {
      const int flat = i * 256 + tid;
      const int c  = flat >> 4;
      const int p0 = (flat & 15) * 4;
      const float4 v = *reinterpret_cast<const float4*>(x + base + (size_t)c * kHW + s * 64 + p0);
      const float vv[4] = {v.x, v.y, v.z, v.w};
#pragma unroll
      for (int j = 0; j < 4; ++j) {
        const int row = sortIdx[s * 64 + p0 + j];
        X[row][xgrp(row, c >> 3) * 8 + (c & 7)] = f2bf(vv[j]);
      }
    }
  }
}

// ---------------- the single fused kernel ----------------
template<typename T>
__device__ void run(const T* __restrict__ x, const void* seg, bool is64,
                    const T* __restrict__ W1, const T* __restrict__ b1,
                    const T* __restrict__ Wr1, const T* __restrict__ br1,
                    const T* __restrict__ Wr2, const T* __restrict__ br2,
                    const T* __restrict__ W3, const T* __restrict__ b3,
                    const T* __restrict__ W4, const T* __restrict__ b4,
                    T* __restrict__ out,
                    unsigned short (*X)[kC], int* sortIdx, int* scnt, int* sbase) {
  const int tid = threadIdx.x, blk = blockIdx.x;
  const int bb  = (blk * PT) / kHW;
  const int hw0 = blk * PT - bb * kHW;

  if (tid < kK) scnt[tid] = 0;
  __syncthreads();
  int myk = 0, myrank = 0;
  if (tid < PT) {
    const int p = blk * PT + tid;
    myk = is64 ? (int)((const long long*)seg)[p] : ((const int*)seg)[p];
    myrank = atomicAdd(&scnt[myk], 1);
  }
  __syncthreads();
  if (tid == 0) {
    int b = 0;
#pragma unroll
    for (int k = 0; k < kK; ++k) { sbase[k] = b; b += ((scnt[k] + 15) >> 4) << 4; }
  }
  __syncthreads();
  if (tid < PT) sortIdx[tid] = sbase[myk] + myrank;
  __syncthreads();

  stage(x, (size_t)bb * kC * kHW + hw0, X, sortIdx, tid);
  __syncthreads();

  // ---- per-wave class chain: no barriers between layers ----
  const int wave = tid >> 6, lane = tid & 63, quad = lane >> 4, col = lane & 15;
  const int k = wave;
  const int n = scnt[k], base = sbase[k];
  const int n_t = (n + 15) >> 4;
  const T* W1k  = W1  + (size_t)k * kC * kC;  const T* b1k  = b1  + (size_t)k * kC;
  const T* Wr1k = Wr1 + (size_t)k * kC * kC;  const T* br1k = br1 + (size_t)k * kC;
  const T* Wr2k = Wr2 + (size_t)k * kC * kC;  const T* br2k = br2 + (size_t)k * kC;
  const T* W3k  = W3  + (size_t)k * kC * kC;  const T* b3k  = b3  + (size_t)k * kC;
  const T* W4k  = W4  + (size_t)k * kO * kC;  const T* b4k  = b4  + (size_t)k * kO;

  for (int t = 0; t < n_t; t += 2) {
    const int t1 = (t + 1 < n_t) ? t + 1 : t;          // odd tail: duplicate
    const int pa = base + t * 16 + col;
    const int pb = base + t1 * 16 + col;
    short4 h0[8], h1[8];
    layer_pair<T, false, false, true >(X, pa, pb, W1k,  b1k,  h0, h1, quad, col);
    layer_pair<T, true,  false, false>(X, pa, pb, Wr1k, br1k, h0, h1, quad, col);
    layer_pair<T, false, true,  false>(X, pa, pb, Wr2k, br2k, h0, h1, quad, col);
    layer_pair<T, true,  false, false>(X, pa, pb, W3k,  b3k,  h0, h1, quad, col);
    layer5<T>(X, pa, pb, W4k, b4k, quad, col);
  }
  __syncthreads();

  // ---- coalesced un-permuted output ----
  const int c = tid >> 2, pc = tid & 3;      // c in 0..63, pc = 32-px chunk
  if (c < kO) {
    const int gi = c >> 2, cl = c & 3;
    T* op = out + ((size_t)bb * kO + c) * kHW + hw0 + pc * 32;
#pragma unroll
    for (int m = 0; m < 4; ++m) {
      unsigned short v[8];
#pragma unroll
      for (int j = 0; j < 8; ++j) {
        const int px = pc * 32 + m * 8 + j;
        const int row = sortIdx[px];
        v[j] = X[row][((gi + row) & 15) * 4 + cl];
      }
      if constexpr (sizeof(T) == 2) {
        *reinterpret_cast<bf16x8*>(op + m * 8) = *reinterpret_cast<const bf16x8*>(v);
      } else {
        float4 f0, f1;
        f0.x = bf2f(v[0]); f0.y = bf2f(v[1]); f0.z = bf2f(v[2]); f0.w = bf2f(v[3]);
        f1.x = bf2f(v[4]); f1.y = bf2f(v[5]); f1.z = bf2f(v[6]); f1.w = bf2f(v[7]);
        *reinterpret_cast<float4*>((float*)op + m * 8)     = f0;
        *reinterpret_cast<float4*>((float*)op + m * 8 + 4) = f1;
      }
    }
  }
}

__global__ __launch_bounds__(256, 2) void fused(
    const void* x, const void* seg,
    const void* W1, const void* b1, const void* Wr1, const void* br1,
    const void* Wr2, const void* br2, const void* W3, const void* b3,
    const void* W4, const void* b4, void* out) {
  __shared__ unsigned short X[MAXR][kC];   // 48 KB
  __shared__ int sortIdx[PT];
  __shared__ int scnt[kK], sbase[kK];
  const int tid = threadIdx.x;

  // dtype sniff (L2-hot heads; identical result for every block)
  const unsigned short h = ((const unsigned short*)x)[tid];
  const int nbad = __syncthreads_count((int)(((h >> 7) & 0xFF) >= 0x84));
  int pred2 = 0;
  if (tid < 64) pred2 = (((const unsigned*)seg)[tid * 2 + 1] != 0);
  const int nonz = __syncthreads_count(pred2);
  const bool isf32 = (nbad > 8);
  const bool is64  = (nonz < 4);

  if (isf32) {
    run<float>((const float*)x, seg, is64,
               (const float*)W1, (const float*)b1,
               (const float*)Wr1, (const float*)br1,
               (const float*)Wr2, (const float*)br2,
               (const float*)W3, (const float*)b3,
               (const float*)W4, (const float*)b4,
               (float*)out, X, sortIdx, scnt, sbase);
  } else {
    run<__hip_bfloat16>((const __hip_bfloat16*)x, seg, is64,
                        (const __hip_bfloat16*)W1, (const __hip_bfloat16*)b1,
                        (const __hip_bfloat16*)Wr1, (const __hip_bfloat16*)br1,
                        (const __hip_bfloat16*)Wr2, (const __hip_bfloat16*)br2,
                        (const __hip_bfloat16*)W3, (const __hip_bfloat16*)b3,
                        (const __hip_bfloat16*)W4, (const __hip_bfloat16*)b4,
                        (__hip_bfloat16*)out, X, sortIdx, scnt, sbase);
  }
}

extern "C" void kernel_launch(void* const* d_in, const int* in_sizes, int n_in,
                              void* d_out, int out_size, void* d_ws, size_t ws_size,
                              hipStream_t stream) {
  (void)in_sizes; (void)n_in; (void)out_size; (void)d_ws; (void)ws_size;
  fused<<<NB, 256, 0, stream>>>(
      d_in[0], d_in[1], d_in[2], d_in[3], d_in[4], d_in[5], d_in[6], d_in[7],
      d_in[8], d_in[9], d_in[10], d_in[11], d_out);
}